// Round 4
// baseline (571.505 us; speedup 1.0000x reference)
//
#include <hip/hip_runtime.h>
#include <hip/hip_bf16.h>
#include <cstdint>
#include <cstddef>

// Problem constants
#define BB   512
#define NN   100
#define HH   768
#define II   1536
#define MM   (BB*NN)          // 51200 rows

typedef __bf16 bf16;
typedef __bf16 bf16x8 __attribute__((ext_vector_type(8)));
typedef float  f32x4  __attribute__((ext_vector_type(4)));

// async global -> LDS, 16B per lane (wave-uniform LDS base + lane*16)
__device__ __forceinline__ void gld_lds16(const bf16* g, bf16* l) {
    __builtin_amdgcn_global_load_lds(
        (const __attribute__((address_space(1))) void*)g,
        (__attribute__((address_space(3))) void*)l, 16, 0, 0);
}

// butterfly add over 16-lane groups via ds_swizzle (BitMode, single DS inst)
template <int PAT>
__device__ __forceinline__ float swz_add(float x) {
    return x + __int_as_float(
        __builtin_amdgcn_ds_swizzle(__float_as_int(x), PAT));
}
__device__ __forceinline__ float red16(float x) {
    x = swz_add<0x041F>(x);   // xor 1
    x = swz_add<0x081F>(x);   // xor 2
    x = swz_add<0x101F>(x);   // xor 4
    x = swz_add<0x201F>(x);   // xor 8
    return x;                 // all 16 lanes hold the group sum
}

// Fast exact-GELU: erf via Abramowitz-Stegun 7.1.26 (|err| <= 1.5e-7)
__device__ __forceinline__ float fast_gelu(float x) {
    const float ax = fabsf(x) * 0.70710678118654752f;   // |x|/sqrt(2)
    const float t  = __builtin_amdgcn_rcpf(fmaf(0.3275911f, ax, 1.0f));
    float p = fmaf(1.061405429f, t, -1.453152027f);
    p = fmaf(p, t, 1.421413741f);
    p = fmaf(p, t, -0.284496736f);
    p = fmaf(p, t, 0.254829592f);
    p = p * t;
    const float e    = __expf(-ax * ax);
    const float erfa = fmaf(-p, e, 1.0f);               // erf(|x|/sqrt2)
    const float erfx = copysignf(erfa, x);
    return 0.5f * x * (1.0f + erfx);
}

// ---------------------------------------------------------------------------
// prep_conv (fused):
//  bid <  6400 : v_emb fp32 [51200][768] -> Av bf16, chunk-XOR-swizzled:
//                stored 16B-chunk position p of row m holds global chunk
//                (p&~3) | ((p&3) ^ ((m>>1)&3)).  Lane-consecutive stored
//                positions -> coalesced writes; XOR only permutes within
//                128B groups -> reads stay cache-line coalesced.
//  bid <  6976 : W1 fp32 [768][1536] -> Wp bf16 [1536][768], transposed,
//                same per-row chunk-XOR swizzle (rows = n)
//  bid == 6976 : gw = gamma*W2
//  bid == 6977 : scal = {sum gamma*W2, sum beta*W2 + b2}
// ---------------------------------------------------------------------------
__global__ __launch_bounds__(256) void prep_conv(
    const float* __restrict__ v, const float* __restrict__ W1,
    const float* __restrict__ gamma, const float* __restrict__ beta,
    const float* __restrict__ W2, const float* __restrict__ b2,
    bf16* __restrict__ Av, bf16* __restrict__ Wp,
    float* __restrict__ gw, float* __restrict__ scal)
{
    const int bid = blockIdx.x;
    if (bid < 6400) {
        // A convert+swizzle: 8 rows per block, 32 threads/row, 3 chunks/thread
        const int r = threadIdx.x >> 5;          // 0..7
        const int j = threadIdx.x & 31;          // 0..31
        const size_t m = (size_t)bid * 8 + r;
        const float* src = v + m * HH;
        bf16* dst = Av + m * HH;
        const int x = (int)((m >> 1) & 3);
        #pragma unroll
        for (int u = 0; u < 3; ++u) {
            const int p = u * 32 + j;                      // stored pos 0..95
            const int g = (p & ~3) | ((p & 3) ^ x);        // content chunk
            float4 a = *(const float4*)(src + g * 8);
            float4 b = *(const float4*)(src + g * 8 + 4);
            bf16x8 o = { (bf16)a.x,(bf16)a.y,(bf16)a.z,(bf16)a.w,
                         (bf16)b.x,(bf16)b.y,(bf16)b.z,(bf16)b.w };
            *(bf16x8*)(dst + p * 8) = o;
        }
    } else if (bid < 6976) {
        // W1 transpose+convert+swizzle: thread -> one 16B output chunk
        const int t = (bid - 6400) * 256 + threadIdx.x;    // 0..147455
        const int n = t % II;                              // lane-consecutive
        const int g = t / II;                              // content chunk 0..95
        const int p = (g & ~3) | ((g & 3) ^ ((n >> 1) & 3));
        bf16x8 o;
        #pragma unroll
        for (int i = 0; i < 8; ++i)
            o[i] = (bf16)W1[(size_t)(g * 8 + i) * II + n]; // coalesced reads
        *(bf16x8*)&Wp[(size_t)n * HH + p * 8] = o;
    } else if (bid == 6976) {
        for (int j = threadIdx.x; j < II; j += 256)
            gw[j] = gamma[j] * W2[j];
    } else {
        float s1 = 0.f, s2 = 0.f;
        for (int j = threadIdx.x; j < II; j += 256) {
            float w2 = W2[j];
            s1 += gamma[j] * w2;
            s2 += beta[j]  * w2;
        }
        #pragma unroll
        for (int off = 32; off; off >>= 1) {
            s1 += __shfl_down(s1, off, 64);
            s2 += __shfl_down(s2, off, 64);
        }
        __shared__ float a1[4], a2[4];
        int lane = threadIdx.x & 63, w = threadIdx.x >> 6;
        if (lane == 0) { a1[w] = s1; a2[w] = s2; }
        __syncthreads();
        if (threadIdx.x == 0) {
            scal[0] = a1[0] + a1[1] + a1[2] + a1[3];
            scal[1] = a2[0] + a2[1] + a2[2] + a2[3] + b2[0];
        }
    }
}

// ---------------------------------------------------------------------------
// gemm_part: 256x128 tile, BK=32, 16x16x32 bf16 MFMA, double-buffered LDS,
// R2-proven sync (stage next -> compute cur -> vmcnt(0)+__syncthreads).
// KEY CHANGE vs R2: wave-tile 128x64 (acc[8][4], 4 waves as 2m x 2n).
// FLOP per LDS-read-byte rises 32 -> 43.7 (B-frag amortized over 8 row
// frags) because R2 was LDS-read-BW bound (MfmaUtil 28% == predicted LDS
// ceiling). LDS 54 KB -> 2 independent blocks/CU (they stagger across each
// other's barriers). Both operands via global_load_lds from pre-swizzled
// bf16 (read xsel = q ^ ((m15>>1)&3): 2-way max bank aliasing, free).
// Grid 2400 = 8 XCDs x 300; 12 nb blocks sharing an A-tile per XCD group.
// Epilogue: +b1, fast GELU, per-row partial LN stats -> part[s][nb][row].
// ---------------------------------------------------------------------------
__global__ __launch_bounds__(256) void gemm_part(
    const bf16* __restrict__ Av, const bf16* __restrict__ Wp,
    const float* __restrict__ b1, const float* __restrict__ gw,
    float* __restrict__ part)
{
    __shared__ bf16  As[2 * 8192];      // 32 KB  (256 rows x 32 per buf)
    __shared__ bf16  Bs[2 * 4096];      // 16 KB  (128 rows x 32 per buf)
    __shared__ float sred[2][256][3];   // 6 KB

    const int tid  = threadIdx.x;
    // 2400 blocks = 8 XCDs x 300; 300 = 25 mb-groups x 12 nb
    const int lin  = (blockIdx.x & 7) * 300 + (blockIdx.x >> 3);
    const int mb   = lin / 12;
    const int nb   = lin % 12;
    const int lane = tid & 63;
    const int w    = tid >> 6;
    const int wm   = w >> 1;            // 0..1  (row half)
    const int wn   = w & 1;             // 0..1  (col half)
    const int m15  = lane & 15;
    const int q    = lane >> 4;         // 0..3
    const int row0 = mb * 256;

    // staging: thread t covers (row = j*64 + t/4, chunk = t&3), 16B each
    const int srow = tid >> 2;          // 0..63
    const int sc   = tid & 3;
    const bf16* aP = Av + (size_t)(row0     + srow) * HH + sc * 8;
    const bf16* bP = Wp + (size_t)(nb * 128 + srow) * HH + sc * 8;
    bf16* asD = As + tid * 8;           // + buf*8192 + j*2048
    bf16* bsD = Bs + tid * 8;           // + buf*4096 + j*2048

    const int xsel = (q ^ ((m15 >> 1) & 3)) * 8;   // read-side swizzle (elems)

    f32x4 acc[8][4] = {};

#define STAGE(T, BUF) do {                                                  \
    const bf16* _a = aP + (T) * 32;                                         \
    const bf16* _b = bP + (T) * 32;                                         \
    gld_lds16(_a,            asD + (BUF) * 8192);                           \
    gld_lds16(_a +  64 * HH, asD + (BUF) * 8192 + 2048);                    \
    gld_lds16(_a + 128 * HH, asD + (BUF) * 8192 + 4096);                    \
    gld_lds16(_a + 192 * HH, asD + (BUF) * 8192 + 6144);                    \
    gld_lds16(_b,            bsD + (BUF) * 4096);                           \
    gld_lds16(_b +  64 * HH, bsD + (BUF) * 4096 + 2048);                    \
} while (0)

#define COMPUTE(BUF) do {                                                   \
    bf16x8 af[8];                                                           \
    _Pragma("unroll")                                                       \
    for (int mt = 0; mt < 8; ++mt)                                          \
        af[mt] = *(const bf16x8*)&As[(BUF)*8192 + (wm*128 + mt*16 + m15)*32 + xsel]; \
    _Pragma("unroll")                                                       \
    for (int nt = 0; nt < 4; ++nt) {                                        \
        bf16x8 bfr = *(const bf16x8*)&Bs[(BUF)*4096 + (wn*64 + nt*16 + m15)*32 + xsel]; \
        _Pragma("unroll")                                                   \
        for (int mt = 0; mt < 8; ++mt)                                      \
            acc[mt][nt] = __builtin_amdgcn_mfma_f32_16x16x32_bf16(          \
                af[mt], bfr, acc[mt][nt], 0, 0, 0);                         \
    }                                                                       \
} while (0)

#define WAITBAR() do {                                                      \
    asm volatile("s_waitcnt vmcnt(0)" ::: "memory");                        \
    __syncthreads();                                                        \
} while (0)

    // ---- prologue: stage kt=0 into buf 0 ----
    STAGE(0, 0);
    WAITBAR();

    // ---- main loop: 24 K-tiles, double-buffered, unrolled by 2 ----
    for (int kt = 0; kt < 22; kt += 2) {
        STAGE(kt + 1, 1); COMPUTE(0); WAITBAR();
        STAGE(kt + 2, 0); COMPUTE(1); WAITBAR();
    }
    STAGE(23, 1); COMPUTE(0); WAITBAR();    // tile 22 from buf0
    COMPUTE(1);                             // tile 23 from buf1

#undef STAGE
#undef COMPUTE
#undef WAITBAR

    // ---- epilogue: +b1, fast GELU, per-row partial stats over 128 cols ----
    float bv[4], gv[4];
    #pragma unroll
    for (int nt = 0; nt < 4; ++nt) {
        const int col = nb*128 + wn*64 + nt*16 + m15;
        bv[nt] = b1[col];
        gv[nt] = gw[col];
    }

    #pragma unroll
    for (int mt = 0; mt < 8; ++mt) {
        #pragma unroll
        for (int r = 0; r < 4; ++r) {
            float x0 = 0.f, x1 = 0.f, x2 = 0.f;
            #pragma unroll
            for (int nt = 0; nt < 4; ++nt) {
                // C/D layout: col = lane&15, row = q*4 + r
                float g = fast_gelu(acc[mt][nt][r] + bv[nt]);
                x0 += g; x1 += g * g; x2 += g * gv[nt];
            }
            x0 = red16(x0); x1 = red16(x1); x2 = red16(x2);
            if (m15 == 0) {
                const int rl = wm*128 + mt*16 + q*4 + r;   // 0..255
                sred[wn][rl][0] = x0;
                sred[wn][rl][1] = x1;
                sred[wn][rl][2] = x2;
            }
        }
    }
    __syncthreads();

    {
        const size_t rg = (size_t)row0 + tid;   // tid 0..255
        #pragma unroll
        for (int s = 0; s < 3; ++s)
            part[(size_t)s * 12 * MM + (size_t)nb * MM + rg]
                = sred[0][tid][s] + sred[1][tid][s];
    }
}

// ---------------------------------------------------------------------------
// score_pred: finish LN + sigmoid for the 100 rows of batch b, write scores,
// then pred = sum(scores), logits = one_hot(clamp(round(pred),0,15))
// ---------------------------------------------------------------------------
__global__ __launch_bounds__(128) void score_pred(
    const float* __restrict__ part, const float* __restrict__ scal,
    float* __restrict__ o_scores, float* __restrict__ o_pred,
    float* __restrict__ o_logits)
{
    const int b = blockIdx.x, t = threadIdx.x;
    float s = 0.f;
    if (t < NN) {
        const size_t row = (size_t)b * NN + t;
        float Sh = 0.f, Shh = 0.f, Shg = 0.f;
        #pragma unroll
        for (int j = 0; j < 12; ++j) {
            Sh  += part[(size_t)0*12*MM + (size_t)j*MM + row];
            Shh += part[(size_t)1*12*MM + (size_t)j*MM + row];
            Shg += part[(size_t)2*12*MM + (size_t)j*MM + row];
        }
        const float mu   = Sh * (1.0f / II);
        const float var  = Shh * (1.0f / II) - mu * mu;
        const float rstd = rsqrtf(var + 1e-5f);
        const float z    = rstd * (Shg - mu * scal[0]) + scal[1];
        s = 1.0f / (1.0f + __expf(-z));
        o_scores[row] = s;
    }
    float v = s;
    #pragma unroll
    for (int off = 32; off; off >>= 1) v += __shfl_down(v, off, 64);
    __shared__ float ssum[2];
    const int lane = t & 63, w = t >> 6;
    if (lane == 0) ssum[w] = v;
    __syncthreads();
    const float p = ssum[0] + ssum[1];
    if (t == 0) o_pred[b] = p;
    if (t < 16) {
        int aid = (int)rintf(p);
        aid = aid < 0 ? 0 : (aid > 15 ? 15 : aid);
        o_logits[b * 16 + t] = (t == aid) ? 1.0f : 0.0f;
    }
}

// ---------------------------------------------------------------------------
extern "C" void kernel_launch(void* const* d_in, const int* in_sizes, int n_in,
                              void* d_out, int out_size, void* d_ws, size_t ws_size,
                              hipStream_t stream)
{
    const float* v_emb = (const float*)d_in[0];
    const float* W1    = (const float*)d_in[1];
    const float* b1    = (const float*)d_in[2];
    const float* gamma = (const float*)d_in[3];
    const float* beta  = (const float*)d_in[4];
    const float* W2    = (const float*)d_in[5];
    const float* b2    = (const float*)d_in[6];

    char* ws = (char*)d_ws;
    size_t off = 0;
    bf16*  Wp   = (bf16*)(ws + off);  off += (size_t)II * HH * 2;      // 2.36 MB
    float* gw   = (float*)(ws + off); off += (size_t)II * 4;
    float* scal = (float*)(ws + off); off += 256;
    float* part = (float*)(ws + off); off += (size_t)MM * 36 * 4;      // 7.37 MB
    bf16*  Av   = (bf16*)(ws + off);  off += (size_t)MM * HH * 2;      // 78.6 MB

    float* out       = (float*)d_out;
    float* o_scores  = out;            // 51200
    float* o_pred    = out + MM;       // 512
    float* o_logits  = out + MM + BB;  // 8192

    hipLaunchKernelGGL(prep_conv, dim3(6978), dim3(256), 0, stream,
                       v_emb, W1, gamma, beta, W2, b2, Av, Wp, gw, scal);
    hipLaunchKernelGGL(gemm_part, dim3((MM / 256) * 12), dim3(256),
                       0, stream, Av, Wp, b1, gw, part);
    hipLaunchKernelGGL(score_pred, dim3(BB), dim3(128), 0, stream,
                       part, scal, o_scores, o_pred, o_logits);
}

// Round 5
// 414.849 us; speedup vs baseline: 1.3776x; 1.3776x over previous
//
#include <hip/hip_runtime.h>
#include <hip/hip_bf16.h>
#include <cstdint>
#include <cstddef>

// Problem constants
#define BB   512
#define NN   100
#define HH   768
#define II   1536
#define MM   (BB*NN)          // 51200 rows

typedef __bf16 bf16;
typedef __bf16 bf16x8 __attribute__((ext_vector_type(8)));
typedef float  f32x4  __attribute__((ext_vector_type(4)));

// async global -> LDS, 16B per lane (wave-uniform LDS base + lane*16)
__device__ __forceinline__ void gld_lds16(const bf16* g, bf16* l) {
    __builtin_amdgcn_global_load_lds(
        (const __attribute__((address_space(1))) void*)g,
        (__attribute__((address_space(3))) void*)l, 16, 0, 0);
}

// butterfly add over 16-lane groups via ds_swizzle (BitMode, single DS inst)
template <int PAT>
__device__ __forceinline__ float swz_add(float x) {
    return x + __int_as_float(
        __builtin_amdgcn_ds_swizzle(__float_as_int(x), PAT));
}
__device__ __forceinline__ float red16(float x) {
    x = swz_add<0x041F>(x);   // xor 1
    x = swz_add<0x081F>(x);   // xor 2
    x = swz_add<0x101F>(x);   // xor 4
    x = swz_add<0x201F>(x);   // xor 8
    return x;                 // all 16 lanes hold the group sum
}

// Fast exact-GELU: erf via Abramowitz-Stegun 7.1.26 (|err| <= 1.5e-7)
__device__ __forceinline__ float fast_gelu(float x) {
    const float ax = fabsf(x) * 0.70710678118654752f;   // |x|/sqrt(2)
    const float t  = __builtin_amdgcn_rcpf(fmaf(0.3275911f, ax, 1.0f));
    float p = fmaf(1.061405429f, t, -1.453152027f);
    p = fmaf(p, t, 1.421413741f);
    p = fmaf(p, t, -0.284496736f);
    p = fmaf(p, t, 0.254829592f);
    p = p * t;
    const float e    = __expf(-ax * ax);
    const float erfa = fmaf(-p, e, 1.0f);               // erf(|x|/sqrt2)
    const float erfx = copysignf(erfa, x);
    return 0.5f * x * (1.0f + erfx);
}

// ---------------------------------------------------------------------------
// prep_conv (fused):
//  bid <  6400 : v_emb fp32 [51200][768] -> Av bf16, chunk-XOR-swizzled:
//                within each aligned 8-chunk (128 B) group, stored 16B-chunk
//                position p of row m holds content chunk
//                (p&~7) | ((p&7) ^ (m&7)).  Involution; baked so the GEMM
//                uses linear global_load_lds + XOR'd ds_read (BK=64 rows,
//                128 B row stride -> key row&7 kills the column-bank clash).
//                Lane-consecutive stored positions -> coalesced writes;
//                XOR permutes only within 128 B -> reads cache-line coalesced.
//  bid <  6976 : W1 fp32 [768][1536] -> Wp bf16 [1536][768], transposed,
//                same per-row chunk-XOR swizzle (rows = n, key n&7)
//  bid == 6976 : gw = gamma*W2
//  bid == 6977 : scal = {sum gamma*W2, sum beta*W2 + b2}
// ---------------------------------------------------------------------------
__global__ __launch_bounds__(256) void prep_conv(
    const float* __restrict__ v, const float* __restrict__ W1,
    const float* __restrict__ gamma, const float* __restrict__ beta,
    const float* __restrict__ W2, const float* __restrict__ b2,
    bf16* __restrict__ Av, bf16* __restrict__ Wp,
    float* __restrict__ gw, float* __restrict__ scal)
{
    const int bid = blockIdx.x;
    if (bid < 6400) {
        // A convert+swizzle: 8 rows per block, 32 threads/row, 3 chunks/thread
        const int r = threadIdx.x >> 5;          // 0..7
        const int j = threadIdx.x & 31;          // 0..31
        const size_t m = (size_t)bid * 8 + r;
        const float* src = v + m * HH;
        bf16* dst = Av + m * HH;
        const int x = (int)(m & 7);
        #pragma unroll
        for (int u = 0; u < 3; ++u) {
            const int p = u * 32 + j;                      // stored pos 0..95
            const int g = (p & ~7) | ((p & 7) ^ x);        // content chunk
            float4 a = *(const float4*)(src + g * 8);
            float4 b = *(const float4*)(src + g * 8 + 4);
            bf16x8 o = { (bf16)a.x,(bf16)a.y,(bf16)a.z,(bf16)a.w,
                         (bf16)b.x,(bf16)b.y,(bf16)b.z,(bf16)b.w };
            *(bf16x8*)(dst + p * 8) = o;
        }
    } else if (bid < 6976) {
        // W1 transpose+convert+swizzle: thread -> one 16B output chunk
        const int t = (bid - 6400) * 256 + threadIdx.x;    // 0..147455
        const int n = t % II;                              // lane-consecutive
        const int g = t / II;                              // content chunk 0..95
        const int p = (g & ~7) | ((g & 7) ^ (n & 7));
        bf16x8 o;
        #pragma unroll
        for (int i = 0; i < 8; ++i)
            o[i] = (bf16)W1[(size_t)(g * 8 + i) * II + n]; // coalesced reads
        *(bf16x8*)&Wp[(size_t)n * HH + p * 8] = o;
    } else if (bid == 6976) {
        for (int j = threadIdx.x; j < II; j += 256)
            gw[j] = gamma[j] * W2[j];
    } else {
        float s1 = 0.f, s2 = 0.f;
        for (int j = threadIdx.x; j < II; j += 256) {
            float w2 = W2[j];
            s1 += gamma[j] * w2;
            s2 += beta[j]  * w2;
        }
        #pragma unroll
        for (int off = 32; off; off >>= 1) {
            s1 += __shfl_down(s1, off, 64);
            s2 += __shfl_down(s2, off, 64);
        }
        __shared__ float a1[4], a2[4];
        int lane = threadIdx.x & 63, w = threadIdx.x >> 6;
        if (lane == 0) { a1[w] = s1; a2[w] = s2; }
        __syncthreads();
        if (threadIdx.x == 0) {
            scal[0] = a1[0] + a1[1] + a1[2] + a1[3];
            scal[1] = a2[0] + a2[1] + a2[2] + a2[3] + b2[0];
        }
    }
}

// ---------------------------------------------------------------------------
// gemm_part: m97-exact structure. 128x128 tile, BK=64, 16x16x32 bf16 MFMA,
// SINGLE-buffered LDS (As/Bs 16 KB each + sred 3 KB = 35 KB -> 4 blocks/CU),
// 2 barriers per K-step, 12 K-steps:
//   STAGE (8x global_load_lds) -> vmcnt(0)+__syncthreads ->
//   COMPUTE (2 kb-phases x {4+4 ds_read_b128, 16 MFMA}) -> __syncthreads
// Cross-block dephasing (4 blocks/CU) covers the per-block drain, as in
// m97/m103 (874-912 TF). acc[4][4] = 64 AGPR, ~128 unified regs.
// Read xsel = ((kb*4+q) ^ (m15&7)): per-16-lane phase each 16B chunk-column
// is hit by exactly 2 lanes -> 2-way bank aliasing (free).
// Grid 4800 = 8 XCDs x 600; 12 nb blocks sharing an A-tile per XCD -> A L2-hot.
// Epilogue: +b1, fast GELU, per-row partial LN stats -> part[s][nb][row].
// ---------------------------------------------------------------------------
__global__ __launch_bounds__(256) void gemm_part(
    const bf16* __restrict__ Av, const bf16* __restrict__ Wp,
    const float* __restrict__ b1, const float* __restrict__ gw,
    float* __restrict__ part)
{
    __shared__ bf16  As[128 * 64];      // 16 KB
    __shared__ bf16  Bs[128 * 64];      // 16 KB
    __shared__ float sred[2][128][3];   // 3 KB

    const int tid  = threadIdx.x;
    // 4800 blocks = 8 XCDs x 600; 600 = 50 mb-groups x 12 nb
    const int lin  = (blockIdx.x & 7) * 600 + (blockIdx.x >> 3);
    const int mb   = lin / 12;
    const int nb   = lin % 12;
    const int lane = tid & 63;
    const int w    = tid >> 6;
    const int wm   = w >> 1;            // 0..1
    const int wn   = w & 1;             // 0..1
    const int m15  = lane & 15;
    const int q    = lane >> 4;         // 0..3
    const int row0 = mb * 128;

    // staging: thread t covers (row = i*32 + t/8, chunk pos = t&7), 16B each
    const int srow = tid >> 3;          // 0..31
    const int sc   = tid & 7;
    const bf16* aP = Av + (size_t)(row0     + srow) * HH + sc * 8;
    const bf16* bP = Wp + (size_t)(nb * 128 + srow) * HH + sc * 8;
    bf16* asD = As + tid * 8;           // call i adds i*2048 elems (4 KB)
    bf16* bsD = Bs + tid * 8;

    f32x4 acc[4][4] = {};

    for (int kt = 0; kt < 12; ++kt) {
        const int ko = kt * 64;
        // ---- stage K-tile kt (A: 4 calls, B: 4 calls; 32 rows each) ----
        #pragma unroll
        for (int i = 0; i < 4; ++i)
            gld_lds16(aP + (size_t)(32 * i) * HH + ko, asD + i * 2048);
        #pragma unroll
        for (int i = 0; i < 4; ++i)
            gld_lds16(bP + (size_t)(32 * i) * HH + ko, bsD + i * 2048);
        asm volatile("s_waitcnt vmcnt(0)" ::: "memory");
        __syncthreads();

        // ---- compute: 2 kb-phases over the 64-wide tile ----
        #pragma unroll
        for (int kb = 0; kb < 2; ++kb) {
            const int xsel = ((kb * 4 + q) ^ (m15 & 7)) * 8;
            bf16x8 af[4];
            #pragma unroll
            for (int mt = 0; mt < 4; ++mt)
                af[mt] = *(const bf16x8*)&As[(wm*64 + mt*16 + m15)*64 + xsel];
            #pragma unroll
            for (int nt = 0; nt < 4; ++nt) {
                bf16x8 bfr = *(const bf16x8*)&Bs[(wn*64 + nt*16 + m15)*64 + xsel];
                #pragma unroll
                for (int mt = 0; mt < 4; ++mt)
                    acc[mt][nt] = __builtin_amdgcn_mfma_f32_16x16x32_bf16(
                        af[mt], bfr, acc[mt][nt], 0, 0, 0);
            }
        }
        __syncthreads();
    }

    // ---- epilogue: +b1, fast GELU, per-row partial stats over 128 cols ----
    float bv[4], gv[4];
    #pragma unroll
    for (int nt = 0; nt < 4; ++nt) {
        const int col = nb*128 + wn*64 + nt*16 + m15;
        bv[nt] = b1[col];
        gv[nt] = gw[col];
    }

    #pragma unroll
    for (int mt = 0; mt < 4; ++mt) {
        #pragma unroll
        for (int r = 0; r < 4; ++r) {
            float x0 = 0.f, x1 = 0.f, x2 = 0.f;
            #pragma unroll
            for (int nt = 0; nt < 4; ++nt) {
                // C/D layout: col = lane&15, row = q*4 + r
                float g = fast_gelu(acc[mt][nt][r] + bv[nt]);
                x0 += g; x1 += g * g; x2 += g * gv[nt];
            }
            x0 = red16(x0); x1 = red16(x1); x2 = red16(x2);
            if (m15 == 0) {
                const int rl = wm*64 + mt*16 + q*4 + r;   // 0..127
                sred[wn][rl][0] = x0;
                sred[wn][rl][1] = x1;
                sred[wn][rl][2] = x2;
            }
        }
    }
    __syncthreads();

    if (tid < 128) {
        const size_t rg = (size_t)row0 + tid;
        #pragma unroll
        for (int s = 0; s < 3; ++s)
            part[(size_t)s * 12 * MM + (size_t)nb * MM + rg]
                = sred[0][tid][s] + sred[1][tid][s];
    }
}

// ---------------------------------------------------------------------------
// score_pred: finish LN + sigmoid for the 100 rows of batch b, write scores,
// then pred = sum(scores), logits = one_hot(clamp(round(pred),0,15))
// ---------------------------------------------------------------------------
__global__ __launch_bounds__(128) void score_pred(
    const float* __restrict__ part, const float* __restrict__ scal,
    float* __restrict__ o_scores, float* __restrict__ o_pred,
    float* __restrict__ o_logits)
{
    const int b = blockIdx.x, t = threadIdx.x;
    float s = 0.f;
    if (t < NN) {
        const size_t row = (size_t)b * NN + t;
        float Sh = 0.f, Shh = 0.f, Shg = 0.f;
        #pragma unroll
        for (int j = 0; j < 12; ++j) {
            Sh  += part[(size_t)0*12*MM + (size_t)j*MM + row];
            Shh += part[(size_t)1*12*MM + (size_t)j*MM + row];
            Shg += part[(size_t)2*12*MM + (size_t)j*MM + row];
        }
        const float mu   = Sh * (1.0f / II);
        const float var  = Shh * (1.0f / II) - mu * mu;
        const float rstd = rsqrtf(var + 1e-5f);
        const float z    = rstd * (Shg - mu * scal[0]) + scal[1];
        s = 1.0f / (1.0f + __expf(-z));
        o_scores[row] = s;
    }
    float v = s;
    #pragma unroll
    for (int off = 32; off; off >>= 1) v += __shfl_down(v, off, 64);
    __shared__ float ssum[2];
    const int lane = t & 63, w = t >> 6;
    if (lane == 0) ssum[w] = v;
    __syncthreads();
    const float p = ssum[0] + ssum[1];
    if (t == 0) o_pred[b] = p;
    if (t < 16) {
        int aid = (int)rintf(p);
        aid = aid < 0 ? 0 : (aid > 15 ? 15 : aid);
        o_logits[b * 16 + t] = (t == aid) ? 1.0f : 0.0f;
    }
}

// ---------------------------------------------------------------------------
extern "C" void kernel_launch(void* const* d_in, const int* in_sizes, int n_in,
                              void* d_out, int out_size, void* d_ws, size_t ws_size,
                              hipStream_t stream)
{
    const float* v_emb = (const float*)d_in[0];
    const float* W1    = (const float*)d_in[1];
    const float* b1    = (const float*)d_in[2];
    const float* gamma = (const float*)d_in[3];
    const float* beta  = (const float*)d_in[4];
    const float* W2    = (const float*)d_in[5];
    const float* b2    = (const float*)d_in[6];

    char* ws = (char*)d_ws;
    size_t off = 0;
    bf16*  Wp   = (bf16*)(ws + off);  off += (size_t)II * HH * 2;      // 2.36 MB
    float* gw   = (float*)(ws + off); off += (size_t)II * 4;
    float* scal = (float*)(ws + off); off += 256;
    float* part = (float*)(ws + off); off += (size_t)MM * 36 * 4;      // 7.37 MB
    bf16*  Av   = (bf16*)(ws + off);  off += (size_t)MM * HH * 2;      // 78.6 MB

    float* out       = (float*)d_out;
    float* o_scores  = out;            // 51200
    float* o_pred    = out + MM;       // 512
    float* o_logits  = out + MM + BB;  // 8192

    hipLaunchKernelGGL(prep_conv, dim3(6978), dim3(256), 0, stream,
                       v_emb, W1, gamma, beta, W2, b2, Av, Wp, gw, scal);
    hipLaunchKernelGGL(gemm_part, dim3((MM / 128) * 12), dim3(256),
                       0, stream, Av, Wp, b1, gw, part);
    hipLaunchKernelGGL(score_pred, dim3(BB), dim3(128), 0, stream,
                       part, scal, o_scores, o_pred, o_logits);
}

// Round 7
// 393.635 us; speedup vs baseline: 1.4519x; 1.0539x over previous
//
#include <hip/hip_runtime.h>
#include <hip/hip_bf16.h>
#include <cstdint>
#include <cstddef>

// Problem constants
#define BB   512
#define NN   100
#define HH   768
#define II   1536
#define MM   (BB*NN)          // 51200 rows

typedef __bf16 bf16;
typedef __bf16 bf16x8 __attribute__((ext_vector_type(8)));
typedef float  f32x4  __attribute__((ext_vector_type(4)));
typedef float  f32x4v __attribute__((ext_vector_type(4)));

// async global -> LDS, 16B per lane (wave-uniform LDS base + lane*16)
__device__ __forceinline__ void gld_lds16(const bf16* g, bf16* l) {
    __builtin_amdgcn_global_load_lds(
        (const __attribute__((address_space(1))) void*)g,
        (__attribute__((address_space(3))) void*)l, 16, 0, 0);
}

// 16-lane-group sum via DPP row_ror rotate-accumulate (VALU pipe, no DS).
// After 4 rotate+add steps every lane of each 16-lane row holds the row sum.
template <int CTRL>
__device__ __forceinline__ float ror_add(float x) {
    int y = __builtin_amdgcn_update_dpp(0, __float_as_int(x), CTRL, 0xF, 0xF, false);
    return x + __int_as_float(y);
}
__device__ __forceinline__ float red16(float x) {
    x = ror_add<0x121>(x);    // row_ror:1
    x = ror_add<0x122>(x);    // row_ror:2
    x = ror_add<0x124>(x);    // row_ror:4
    x = ror_add<0x128>(x);    // row_ror:8
    return x;
}

// Fast exact-GELU: erf via Abramowitz-Stegun 7.1.26 (|err| <= 1.5e-7)
__device__ __forceinline__ float fast_gelu(float x) {
    const float ax = fabsf(x) * 0.70710678118654752f;   // |x|/sqrt(2)
    const float t  = __builtin_amdgcn_rcpf(fmaf(0.3275911f, ax, 1.0f));
    float p = fmaf(1.061405429f, t, -1.453152027f);
    p = fmaf(p, t, 1.421413741f);
    p = fmaf(p, t, -0.284496736f);
    p = fmaf(p, t, 0.254829592f);
    p = p * t;
    const float e    = __expf(-ax * ax);
    const float erfa = fmaf(-p, e, 1.0f);               // erf(|x|/sqrt2)
    const float erfx = copysignf(erfa, x);
    return 0.5f * x * (1.0f + erfx);
}

// ---------------------------------------------------------------------------
// prep_conv (fused):
//  bid <  6400 : v_emb fp32 [51200][768] -> Av bf16, chunk-XOR-swizzled:
//                within each aligned 8-chunk (128 B) group, stored 16B-chunk
//                position p of row m holds content chunk (p&~7)|((p&7)^(m&7)).
//                v_emb is read NON-TEMPORAL (read-once; keeps Av resident in
//                L3 so the GEMM's 12x A re-reads are L3 hits, not HBM).
//  bid <  6976 : W1 fp32 [768][1536] -> Wp bf16 [1536][768], transposed,
//                same per-row chunk-XOR swizzle (rows = n, key n&7)
//  bid == 6976 : gw = gamma*W2
//  bid == 6977 : scal = {sum gamma*W2, sum beta*W2 + b2}
// ---------------------------------------------------------------------------
__global__ __launch_bounds__(256) void prep_conv(
    const float* __restrict__ v, const float* __restrict__ W1,
    const float* __restrict__ gamma, const float* __restrict__ beta,
    const float* __restrict__ W2, const float* __restrict__ b2,
    bf16* __restrict__ Av, bf16* __restrict__ Wp,
    float* __restrict__ gw, float* __restrict__ scal)
{
    const int bid = blockIdx.x;
    if (bid < 6400) {
        // A convert+swizzle: 8 rows per block, 32 threads/row, 3 chunks/thread
        const int r = threadIdx.x >> 5;          // 0..7
        const int j = threadIdx.x & 31;          // 0..31
        const size_t m = (size_t)bid * 8 + r;
        const float* src = v + m * HH;
        bf16* dst = Av + m * HH;
        const int x = (int)(m & 7);
        #pragma unroll
        for (int u = 0; u < 3; ++u) {
            const int p = u * 32 + j;                      // stored pos 0..95
            const int g = (p & ~7) | ((p & 7) ^ x);        // content chunk
            f32x4v a = __builtin_nontemporal_load((const f32x4v*)(src + g * 8));
            f32x4v b = __builtin_nontemporal_load((const f32x4v*)(src + g * 8 + 4));
            bf16x8 o = { (bf16)a[0],(bf16)a[1],(bf16)a[2],(bf16)a[3],
                         (bf16)b[0],(bf16)b[1],(bf16)b[2],(bf16)b[3] };
            *(bf16x8*)(dst + p * 8) = o;
        }
    } else if (bid < 6976) {
        // W1 transpose+convert+swizzle: thread -> one 16B output chunk
        const int t = (bid - 6400) * 256 + threadIdx.x;    // 0..147455
        const int n = t % II;                              // lane-consecutive
        const int g = t / II;                              // content chunk 0..95
        const int p = (g & ~7) | ((g & 7) ^ (n & 7));
        bf16x8 o;
        #pragma unroll
        for (int i = 0; i < 8; ++i)
            o[i] = (bf16)W1[(size_t)(g * 8 + i) * II + n]; // coalesced reads
        *(bf16x8*)&Wp[(size_t)n * HH + p * 8] = o;
    } else if (bid == 6976) {
        for (int j = threadIdx.x; j < II; j += 256)
            gw[j] = gamma[j] * W2[j];
    } else {
        float s1 = 0.f, s2 = 0.f;
        for (int j = threadIdx.x; j < II; j += 256) {
            float w2 = W2[j];
            s1 += gamma[j] * w2;
            s2 += beta[j]  * w2;
        }
        #pragma unroll
        for (int off = 32; off; off >>= 1) {
            s1 += __shfl_down(s1, off, 64);
            s2 += __shfl_down(s2, off, 64);
        }
        __shared__ float a1[4], a2[4];
        int lane = threadIdx.x & 63, w = threadIdx.x >> 6;
        if (lane == 0) { a1[w] = s1; a2[w] = s2; }
        __syncthreads();
        if (threadIdx.x == 0) {
            scal[0] = a1[0] + a1[1] + a1[2] + a1[3];
            scal[1] = a2[0] + a2[1] + a2[2] + a2[3] + b2[0];
        }
    }
}

// ---------------------------------------------------------------------------
// gemm_part: m97-exact structure (R5-proven, 192 us). 128x128 tile, BK=64,
// 16x16x32 bf16 MFMA, SINGLE-buffered LDS (35 KB -> 4 blocks/CU),
// 2 barriers per K-step, 12 K-steps. Cross-block dephasing covers drains.
// Read xsel = ((kb*4+q) ^ (m15&7)): 2-way bank aliasing max (free).
// Epilogue: +b1, fast GELU, per-row partial LN stats via DPP row-reduce
// (VALU, off the contended DS pipe) -> part[s][nb][row].
// ---------------------------------------------------------------------------
__global__ __launch_bounds__(256) void gemm_part(
    const bf16* __restrict__ Av, const bf16* __restrict__ Wp,
    const float* __restrict__ b1, const float* __restrict__ gw,
    float* __restrict__ part)
{
    __shared__ bf16  As[128 * 64];      // 16 KB
    __shared__ bf16  Bs[128 * 64];      // 16 KB
    __shared__ float sred[2][128][3];   // 3 KB

    const int tid  = threadIdx.x;
    // 4800 blocks = 8 XCDs x 600; 600 = 50 mb-groups x 12 nb
    const int lin  = (blockIdx.x & 7) * 600 + (blockIdx.x >> 3);
    const int mb   = lin / 12;
    const int nb   = lin % 12;
    const int lane = tid & 63;
    const int w    = tid >> 6;
    const int wm   = w >> 1;            // 0..1
    const int wn   = w & 1;             // 0..1
    const int m15  = lane & 15;
    const int q    = lane >> 4;         // 0..3
    const int row0 = mb * 128;

    // staging: thread t covers (row = i*32 + t/8, chunk pos = t&7), 16B each
    const int srow = tid >> 3;          // 0..31
    const int sc   = tid & 7;
    const bf16* aP = Av + (size_t)(row0     + srow) * HH + sc * 8;
    const bf16* bP = Wp + (size_t)(nb * 128 + srow) * HH + sc * 8;
    bf16* asD = As + tid * 8;           // call i adds i*2048 elems (4 KB)
    bf16* bsD = Bs + tid * 8;

    f32x4 acc[4][4] = {};

    for (int kt = 0; kt < 12; ++kt) {
        const int ko = kt * 64;
        // ---- stage K-tile kt (A: 4 calls, B: 4 calls; 32 rows each) ----
        #pragma unroll
        for (int i = 0; i < 4; ++i)
            gld_lds16(aP + (size_t)(32 * i) * HH + ko, asD + i * 2048);
        #pragma unroll
        for (int i = 0; i < 4; ++i)
            gld_lds16(bP + (size_t)(32 * i) * HH + ko, bsD + i * 2048);
        asm volatile("s_waitcnt vmcnt(0)" ::: "memory");
        __syncthreads();

        // ---- compute: 2 kb-phases over the 64-wide tile ----
        #pragma unroll
        for (int kb = 0; kb < 2; ++kb) {
            const int xsel = ((kb * 4 + q) ^ (m15 & 7)) * 8;
            bf16x8 af[4];
            #pragma unroll
            for (int mt = 0; mt < 4; ++mt)
                af[mt] = *(const bf16x8*)&As[(wm*64 + mt*16 + m15)*64 + xsel];
            #pragma unroll
            for (int nt = 0; nt < 4; ++nt) {
                bf16x8 bfr = *(const bf16x8*)&Bs[(wn*64 + nt*16 + m15)*64 + xsel];
                #pragma unroll
                for (int mt = 0; mt < 4; ++mt)
                    acc[mt][nt] = __builtin_amdgcn_mfma_f32_16x16x32_bf16(
                        af[mt], bfr, acc[mt][nt], 0, 0, 0);
            }
        }
        __syncthreads();
    }

    // ---- epilogue: +b1, fast GELU, per-row partial stats over 128 cols ----
    float bv[4], gv[4];
    #pragma unroll
    for (int nt = 0; nt < 4; ++nt) {
        const int col = nb*128 + wn*64 + nt*16 + m15;
        bv[nt] = b1[col];
        gv[nt] = gw[col];
    }

    #pragma unroll
    for (int mt = 0; mt < 4; ++mt) {
        #pragma unroll
        for (int r = 0; r < 4; ++r) {
            float x0 = 0.f, x1 = 0.f, x2 = 0.f;
            #pragma unroll
            for (int nt = 0; nt < 4; ++nt) {
                // C/D layout: col = lane&15, row = q*4 + r
                float g = fast_gelu(acc[mt][nt][r] + bv[nt]);
                x0 += g; x1 += g * g; x2 += g * gv[nt];
            }
            x0 = red16(x0); x1 = red16(x1); x2 = red16(x2);
            if (m15 == 0) {
                const int rl = wm*64 + mt*16 + q*4 + r;   // 0..127
                sred[wn][rl][0] = x0;
                sred[wn][rl][1] = x1;
                sred[wn][rl][2] = x2;
            }
        }
    }
    __syncthreads();

    if (tid < 128) {
        const size_t rg = (size_t)row0 + tid;
        #pragma unroll
        for (int s = 0; s < 3; ++s)
            part[(size_t)s * 12 * MM + (size_t)nb * MM + rg]
                = sred[0][tid][s] + sred[1][tid][s];
    }
}

// ---------------------------------------------------------------------------
// score_pred: finish LN + sigmoid for the 100 rows of batch b, write scores,
// then pred = sum(scores), logits = one_hot(clamp(round(pred),0,15))
// ---------------------------------------------------------------------------
__global__ __launch_bounds__(128) void score_pred(
    const float* __restrict__ part, const float* __restrict__ scal,
    float* __restrict__ o_scores, float* __restrict__ o_pred,
    float* __restrict__ o_logits)
{
    const int b = blockIdx.x, t = threadIdx.x;
    float s = 0.f;
    if (t < NN) {
        const size_t row = (size_t)b * NN + t;
        float Sh = 0.f, Shh = 0.f, Shg = 0.f;
        #pragma unroll
        for (int j = 0; j < 12; ++j) {
            Sh  += part[(size_t)0*12*MM + (size_t)j*MM + row];
            Shh += part[(size_t)1*12*MM + (size_t)j*MM + row];
            Shg += part[(size_t)2*12*MM + (size_t)j*MM + row];
        }
        const float mu   = Sh * (1.0f / II);
        const float var  = Shh * (1.0f / II) - mu * mu;
        const float rstd = rsqrtf(var + 1e-5f);
        const float z    = rstd * (Shg - mu * scal[0]) + scal[1];
        s = 1.0f / (1.0f + __expf(-z));
        o_scores[row] = s;
    }
    float v = s;
    #pragma unroll
    for (int off = 32; off; off >>= 1) v += __shfl_down(v, off, 64);
    __shared__ float ssum[2];
    const int lane = t & 63, w = t >> 6;
    if (lane == 0) ssum[w] = v;
    __syncthreads();
    const float p = ssum[0] + ssum[1];
    if (t == 0) o_pred[b] = p;
    if (t < 16) {
        int aid = (int)rintf(p);
        aid = aid < 0 ? 0 : (aid > 15 ? 15 : aid);
        o_logits[b * 16 + t] = (t == aid) ? 1.0f : 0.0f;
    }
}

// ---------------------------------------------------------------------------
extern "C" void kernel_launch(void* const* d_in, const int* in_sizes, int n_in,
                              void* d_out, int out_size, void* d_ws, size_t ws_size,
                              hipStream_t stream)
{
    const float* v_emb = (const float*)d_in[0];
    const float* W1    = (const float*)d_in[1];
    const float* b1    = (const float*)d_in[2];
    const float* gamma = (const float*)d_in[3];
    const float* beta  = (const float*)d_in[4];
    const float* W2    = (const float*)d_in[5];
    const float* b2    = (const float*)d_in[6];

    char* ws = (char*)d_ws;
    size_t off = 0;
    bf16*  Wp   = (bf16*)(ws + off);  off += (size_t)II * HH * 2;      // 2.36 MB
    float* gw   = (float*)(ws + off); off += (size_t)II * 4;
    float* scal = (float*)(ws + off); off += 256;
    float* part = (float*)(ws + off); off += (size_t)MM * 36 * 4;      // 7.37 MB
    bf16*  Av   = (bf16*)(ws + off);  off += (size_t)MM * HH * 2;      // 78.6 MB

    float* out       = (float*)d_out;
    float* o_scores  = out;            // 51200
    float* o_pred    = out + MM;       // 512
    float* o_logits  = out + MM + BB;  // 8192

    hipLaunchKernelGGL(prep_conv, dim3(6978), dim3(256), 0, stream,
                       v_emb, W1, gamma, beta, W2, b2, Av, Wp, gw, scal);
    hipLaunchKernelGGL(gemm_part, dim3((MM / 128) * 12), dim3(256),
                       0, stream, Av, Wp, b1, gw, part);
    hipLaunchKernelGGL(score_pred, dim3(BB), dim3(128), 0, stream,
                       part, scal, o_scores, o_pred, o_logits);
}